// Round 3
// baseline (301.001 us; speedup 1.0000x reference)
//
#include <hip/hip_runtime.h>
#include <math.h>

#define COS_EPS 1e-8f

typedef float vfloat4 __attribute__((ext_vector_type(4)));

// One wave (64 lanes) per sample, grid-stride unrolled x2 for memory-level
// parallelism. Plain cached loads (NT loads regressed 2x in R2: they bypass
// L2/LLC; the harness's input-restore copy leaves embeddings LLC-warm).
// Per sample: lane loads float4 chunks of the embedding row and the gathered
// prototype row; computes dot, |e|^2, |p|^2; 64-lane butterfly reduce;
// lane 0 accumulates cos. Block partial -> d_ws; ticket-atomic "last block"
// reduces all partials and writes 1 - mean directly to d_out.
__global__ __launch_bounds__(256) void assignment_loss_kernel(
    const float* __restrict__ emb,      // [B, D]
    const int*   __restrict__ labels,   // [B]
    const float* __restrict__ protos,   // [C, D]
    float*        __restrict__ partials, // [gridDim.x]
    unsigned int* __restrict__ ticket,   // [1], pre-zeroed
    float*        __restrict__ out,      // [1]
    int B, int D, float invB)
{
    const int lane          = threadIdx.x & 63;
    const int wave_in_block = threadIdx.x >> 6;
    const int waves_per_blk = blockDim.x >> 6;
    const int global_wave   = blockIdx.x * waves_per_blk + wave_in_block;
    const int n_waves       = gridDim.x * waves_per_blk;
    const int nchunks       = D >> 8;   // 256 floats per chunk (64 lanes * float4)

    float local = 0.0f;

    for (int s0 = global_wave; s0 < B; s0 += 2 * n_waves) {
        const int s1    = s0 + n_waves;
        const bool has1 = (s1 < B);

        const int l0 = labels[s0];
        const int l1 = has1 ? labels[s1] : 0;

        const vfloat4* __restrict__ e0 = (const vfloat4*)(emb    + (size_t)s0 * (size_t)D);
        const vfloat4* __restrict__ p0 = (const vfloat4*)(protos + (size_t)l0 * (size_t)D);
        const vfloat4* __restrict__ e1 = (const vfloat4*)(emb    + (size_t)(has1 ? s1 : s0) * (size_t)D);
        const vfloat4* __restrict__ p1 = (const vfloat4*)(protos + (size_t)l1 * (size_t)D);

        float dot0 = 0.f, esq0 = 0.f, psq0 = 0.f;
        float dot1 = 0.f, esq1 = 0.f, psq1 = 0.f;

        #pragma unroll
        for (int c = 0; c < 2; ++c) {           // D=512 -> exactly 2 chunks
            if (c < nchunks) {
                vfloat4 ev0 = e0[c * 64 + lane];
                vfloat4 pv0 = p0[c * 64 + lane];
                vfloat4 ev1 = e1[c * 64 + lane];
                vfloat4 pv1 = p1[c * 64 + lane];

                dot0 = fmaf(ev0.x, pv0.x, fmaf(ev0.y, pv0.y, fmaf(ev0.z, pv0.z, fmaf(ev0.w, pv0.w, dot0))));
                esq0 = fmaf(ev0.x, ev0.x, fmaf(ev0.y, ev0.y, fmaf(ev0.z, ev0.z, fmaf(ev0.w, ev0.w, esq0))));
                psq0 = fmaf(pv0.x, pv0.x, fmaf(pv0.y, pv0.y, fmaf(pv0.z, pv0.z, fmaf(pv0.w, pv0.w, psq0))));
                dot1 = fmaf(ev1.x, pv1.x, fmaf(ev1.y, pv1.y, fmaf(ev1.z, pv1.z, fmaf(ev1.w, pv1.w, dot1))));
                esq1 = fmaf(ev1.x, ev1.x, fmaf(ev1.y, ev1.y, fmaf(ev1.z, ev1.z, fmaf(ev1.w, ev1.w, esq1))));
                psq1 = fmaf(pv1.x, pv1.x, fmaf(pv1.y, pv1.y, fmaf(pv1.z, pv1.z, fmaf(pv1.w, pv1.w, psq1))));
            }
        }
        // generic tail for D > 512 (not hit for this problem shape)
        for (int c = 2; c < nchunks; ++c) {
            vfloat4 ev0 = e0[c * 64 + lane];
            vfloat4 pv0 = p0[c * 64 + lane];
            vfloat4 ev1 = e1[c * 64 + lane];
            vfloat4 pv1 = p1[c * 64 + lane];
            dot0 = fmaf(ev0.x, pv0.x, fmaf(ev0.y, pv0.y, fmaf(ev0.z, pv0.z, fmaf(ev0.w, pv0.w, dot0))));
            esq0 = fmaf(ev0.x, ev0.x, fmaf(ev0.y, ev0.y, fmaf(ev0.z, ev0.z, fmaf(ev0.w, ev0.w, esq0))));
            psq0 = fmaf(pv0.x, pv0.x, fmaf(pv0.y, pv0.y, fmaf(pv0.z, pv0.z, fmaf(pv0.w, pv0.w, psq0))));
            dot1 = fmaf(ev1.x, pv1.x, fmaf(ev1.y, pv1.y, fmaf(ev1.z, pv1.z, fmaf(ev1.w, pv1.w, dot1))));
            esq1 = fmaf(ev1.x, ev1.x, fmaf(ev1.y, ev1.y, fmaf(ev1.z, ev1.z, fmaf(ev1.w, ev1.w, esq1))));
            psq1 = fmaf(pv1.x, pv1.x, fmaf(pv1.y, pv1.y, fmaf(pv1.z, pv1.z, fmaf(pv1.w, pv1.w, psq1))));
        }

        // 64-lane butterfly reduction (wave = 64 on CDNA)
        #pragma unroll
        for (int off = 32; off > 0; off >>= 1) {
            dot0 += __shfl_xor(dot0, off, 64);
            esq0 += __shfl_xor(esq0, off, 64);
            psq0 += __shfl_xor(psq0, off, 64);
            dot1 += __shfl_xor(dot1, off, 64);
            esq1 += __shfl_xor(esq1, off, 64);
            psq1 += __shfl_xor(psq1, off, 64);
        }

        if (lane == 0) {
            float en0 = fmaxf(sqrtf(esq0), COS_EPS);  // torch F.cosine_similarity eps semantics
            float pn0 = fmaxf(sqrtf(psq0), COS_EPS);
            local += dot0 / (en0 * pn0);
            if (has1) {
                float en1 = fmaxf(sqrtf(esq1), COS_EPS);
                float pn1 = fmaxf(sqrtf(psq1), COS_EPS);
                local += dot1 / (en1 * pn1);
            }
        }
    }

    // block reduction: one partial per wave -> LDS -> per-block partial
    __shared__ float smem[8];
    __shared__ bool  am_last;
    if (lane == 0) smem[wave_in_block] = local;
    __syncthreads();
    if (threadIdx.x == 0) {
        float bs = 0.0f;
        for (int w = 0; w < waves_per_blk; ++w) bs += smem[w];
        partials[blockIdx.x] = bs;
        __threadfence();                          // make partial visible device-wide
        unsigned t = atomicAdd(ticket, 1u);       // device-scope by default
        am_last = (t == (unsigned)gridDim.x - 1u);
    }
    __syncthreads();

    if (am_last) {
        __threadfence();                          // acquire: see all partials
        float s = 0.0f;
        for (int i = threadIdx.x; i < gridDim.x; i += blockDim.x) s += partials[i];
        #pragma unroll
        for (int off = 32; off > 0; off >>= 1) s += __shfl_xor(s, off, 64);
        if (lane == 0) smem[wave_in_block] = s;
        __syncthreads();
        if (threadIdx.x == 0) {
            float total = 0.0f;
            for (int w = 0; w < waves_per_blk; ++w) total += smem[w];
            out[0] = 1.0f - total * invB;
        }
    }
}

extern "C" void kernel_launch(void* const* d_in, const int* in_sizes, int n_in,
                              void* d_out, int out_size, void* d_ws, size_t ws_size,
                              hipStream_t stream) {
    const float* emb    = (const float*)d_in[0];   // [B, D] float32
    const int*   labels = (const int*)  d_in[1];   // [B] int
    const float* protos = (const float*)d_in[2];   // [C, D] float32
    float*       out    = (float*)d_out;           // scalar float32

    unsigned int* ticket   = (unsigned int*)d_ws;                 // 4 B, must be zero
    float*        partials = (float*)((char*)d_ws + 256);         // [grid]

    const int B = in_sizes[1];
    const int D = in_sizes[0] / B;                 // 512

    hipMemsetAsync(ticket, 0, sizeof(unsigned int), stream);      // d_ws is poisoned 0xAA each call

    const int block = 256;                         // 4 waves/block
    const int grid  = 2048;                        // 8 blocks/CU target, 8192 waves
    assignment_loss_kernel<<<grid, block, 0, stream>>>(
        emb, labels, protos, partials, ticket, out, B, D, 1.0f / (float)B);
}

// Round 4
// 245.102 us; speedup vs baseline: 1.2281x; 1.2281x over previous
//
#include <hip/hip_runtime.h>
#include <math.h>

#define COS_EPS 1e-8f

typedef float vfloat4 __attribute__((ext_vector_type(4)));

__device__ __forceinline__ float dot4(vfloat4 a, vfloat4 b) {
    return fmaf(a.x, b.x, fmaf(a.y, b.y, fmaf(a.z, b.z, a.w * b.w)));
}

// ---------------- K1: inverse norms for all emb rows and proto rows ----------------
// One wave per 2KB row, streaming. inv[r] = 1/max(sqrt(sum sq), eps).
__global__ __launch_bounds__(256) void row_inv_norm_kernel(
    const float* __restrict__ emb,     // [B, D]
    const float* __restrict__ protos,  // [C, D]
    float* __restrict__ inv_en,        // [B]
    float* __restrict__ inv_pn,        // [C]
    int B, int C, int D)
{
    const int lane = threadIdx.x & 63;
    const int gw   = (blockIdx.x * blockDim.x + threadIdx.x) >> 6;
    const int nw   = (gridDim.x * blockDim.x) >> 6;
    const int nchunks = D >> 8;
    const int R = B + C;

    for (int r = gw; r < R; r += nw) {
        const float* row = (r < B) ? (emb + (size_t)r * (size_t)D)
                                   : (protos + (size_t)(r - B) * (size_t)D);
        const vfloat4* v = (const vfloat4*)row;
        float ssq = 0.0f;
        if (nchunks == 2) {            // D == 512 fast path: both loads independent
            vfloat4 a = v[lane];
            vfloat4 b = v[64 + lane];
            ssq = dot4(a, a) + dot4(b, b);
        } else {
            for (int c = 0; c < nchunks; ++c) {
                vfloat4 a = v[c * 64 + lane];
                ssq += dot4(a, a);
            }
        }
        #pragma unroll
        for (int off = 32; off > 0; off >>= 1) ssq += __shfl_xor(ssq, off, 64);
        if (lane == 0) {
            float inv = 1.0f / fmaxf(sqrtf(ssq), COS_EPS);  // torch eps semantics
            if (r < B) inv_en[r] = inv; else inv_pn[r - B] = inv;
        }
    }
}

// ---------------- K2: drain-free weighted dot accumulation ----------------
// sum_s cos_s = sum_s w_s * dot_s, w_s = inv_en[s]*inv_pn[l_s].
// Each lane accumulates w_s * partial_dot(lane, s) into ONE scalar; the
// cross-lane reduction happens once at kernel end. No per-sample vmcnt
// drain -> loads from 4 unrolled samples stay in flight together.
__global__ __launch_bounds__(256) void weighted_dot_kernel(
    const float* __restrict__ emb,      // [B, D]
    const int*   __restrict__ labels,   // [B]
    const float* __restrict__ protos,   // [C, D]
    const float* __restrict__ inv_en,   // [B]
    const float* __restrict__ inv_pn,   // [C]
    float*       __restrict__ acc,      // [1] pre-zeroed
    int B, int D)
{
    const int lane = threadIdx.x & 63;
    const int wib  = threadIdx.x >> 6;
    const int wpb  = blockDim.x >> 6;
    const int gw   = blockIdx.x * wpb + wib;
    const int nw   = gridDim.x * wpb;
    const int nchunks = D >> 8;

    float local = 0.0f;

    if (nchunks == 2 && (B % (4 * nw)) == 0) {
        // exact-trip, guard-free, 4-sample unroll: 16 independent 1KB loads in flight
        for (int s = gw; s < B; s += 4 * nw) {
            const int s0 = s, s1 = s + nw, s2 = s + 2 * nw, s3 = s + 3 * nw;
            const int l0 = labels[s0], l1 = labels[s1], l2 = labels[s2], l3 = labels[s3];

            const vfloat4* e0 = (const vfloat4*)(emb    + (size_t)s0 * (size_t)D);
            const vfloat4* e1 = (const vfloat4*)(emb    + (size_t)s1 * (size_t)D);
            const vfloat4* e2 = (const vfloat4*)(emb    + (size_t)s2 * (size_t)D);
            const vfloat4* e3 = (const vfloat4*)(emb    + (size_t)s3 * (size_t)D);
            const vfloat4* p0 = (const vfloat4*)(protos + (size_t)l0 * (size_t)D);
            const vfloat4* p1 = (const vfloat4*)(protos + (size_t)l1 * (size_t)D);
            const vfloat4* p2 = (const vfloat4*)(protos + (size_t)l2 * (size_t)D);
            const vfloat4* p3 = (const vfloat4*)(protos + (size_t)l3 * (size_t)D);

            vfloat4 ea0 = e0[lane],      eb0 = e0[64 + lane];
            vfloat4 ea1 = e1[lane],      eb1 = e1[64 + lane];
            vfloat4 ea2 = e2[lane],      eb2 = e2[64 + lane];
            vfloat4 ea3 = e3[lane],      eb3 = e3[64 + lane];
            vfloat4 pa0 = p0[lane],      pb0 = p0[64 + lane];
            vfloat4 pa1 = p1[lane],      pb1 = p1[64 + lane];
            vfloat4 pa2 = p2[lane],      pb2 = p2[64 + lane];
            vfloat4 pa3 = p3[lane],      pb3 = p3[64 + lane];

            const float w0 = inv_en[s0] * inv_pn[l0];
            const float w1 = inv_en[s1] * inv_pn[l1];
            const float w2 = inv_en[s2] * inv_pn[l2];
            const float w3 = inv_en[s3] * inv_pn[l3];

            const float pd0 = dot4(ea0, pa0) + dot4(eb0, pb0);
            const float pd1 = dot4(ea1, pa1) + dot4(eb1, pb1);
            const float pd2 = dot4(ea2, pa2) + dot4(eb2, pb2);
            const float pd3 = dot4(ea3, pa3) + dot4(eb3, pb3);

            local = fmaf(pd0, w0, fmaf(pd1, w1, fmaf(pd2, w2, fmaf(pd3, w3, local))));
        }
    } else {
        // generic fallback
        for (int s = gw; s < B; s += nw) {
            const int l = labels[s];
            const vfloat4* e = (const vfloat4*)(emb    + (size_t)s * (size_t)D);
            const vfloat4* p = (const vfloat4*)(protos + (size_t)l * (size_t)D);
            float pd = 0.0f;
            for (int c = 0; c < nchunks; ++c)
                pd += dot4(e[c * 64 + lane], p[c * 64 + lane]);
            local = fmaf(pd, inv_en[s] * inv_pn[l], local);
        }
    }

    // single reduction at kernel end: wave butterfly -> LDS -> one atomic/block
    #pragma unroll
    for (int off = 32; off > 0; off >>= 1) local += __shfl_xor(local, off, 64);

    __shared__ float smem[8];
    if (lane == 0) smem[wib] = local;
    __syncthreads();
    if (threadIdx.x == 0) {
        float bs = 0.0f;
        for (int w = 0; w < wpb; ++w) bs += smem[w];
        atomicAdd(acc, bs);
    }
}

__global__ void assignment_loss_finalize(const float* __restrict__ acc,
                                         float* __restrict__ out,
                                         float invB)
{
    out[0] = 1.0f - acc[0] * invB;
}

extern "C" void kernel_launch(void* const* d_in, const int* in_sizes, int n_in,
                              void* d_out, int out_size, void* d_ws, size_t ws_size,
                              hipStream_t stream) {
    const float* emb    = (const float*)d_in[0];   // [B, D] float32
    const int*   labels = (const int*)  d_in[1];   // [B] int32
    const float* protos = (const float*)d_in[2];   // [C, D] float32
    float*       out    = (float*)d_out;           // scalar float32

    const int B = in_sizes[1];
    const int D = in_sizes[0] / B;                 // 512
    const int C = in_sizes[2] / D;                 // 10000

    float* acc    = (float*)d_ws;                              // 4 B
    float* inv_en = (float*)((char*)d_ws + 256);               // B floats
    float* inv_pn = inv_en + B;                                // C floats

    hipMemsetAsync(acc, 0, sizeof(float), stream);

    // K1: 2048 blocks x 4 waves = 8192 waves streaming 75536 rows
    row_inv_norm_kernel<<<2048, 256, 0, stream>>>(emb, protos, inv_en, inv_pn, B, C, D);
    // K2: 1024 blocks x 4 waves = 4096 waves, 16 samples/wave, 4 unrolled
    weighted_dot_kernel<<<1024, 256, 0, stream>>>(emb, labels, protos, inv_en, inv_pn, acc, B, D);
    assignment_loss_finalize<<<1, 1, 0, stream>>>(acc, out, 1.0f / (float)B);
}

// Round 5
// 209.616 us; speedup vs baseline: 1.4360x; 1.1693x over previous
//
#include <hip/hip_runtime.h>
#include <math.h>

#define COS_EPS 1e-8f

typedef float vfloat4 __attribute__((ext_vector_type(4)));

__device__ __forceinline__ float dot4(vfloat4 a, vfloat4 b) {
    return fmaf(a.x, b.x, fmaf(a.y, b.y, fmaf(a.z, b.z, a.w * b.w)));
}

// R1 structure (single pass, wave-per-sample, grid 1024, atomicAdd tail,
// separate finalize, NO device-scope fences) + explicit 2-deep software
// pipeline: labels prefetched 2 iterations ahead, row loads issued 1
// iteration ahead, so sample s's butterfly overlaps sample s+1's loads.
__global__ __launch_bounds__(256) void assignment_loss_kernel(
    const float* __restrict__ emb,      // [B, D]
    const int*   __restrict__ labels,   // [B]
    const float* __restrict__ protos,   // [C, D]
    float*       __restrict__ acc,      // [1] pre-zeroed
    int B, int D)
{
    const int lane = threadIdx.x & 63;
    const int wib  = threadIdx.x >> 6;
    const int wpb  = blockDim.x >> 6;
    const int gw   = blockIdx.x * wpb + wib;
    const int nw   = gridDim.x * wpb;

    float local = 0.0f;

    if (D == 512 && (B % nw) == 0 && (B / nw) >= 3) {
        const int iters = B / nw;          // 16 for B=65536, nw=4096
        int s = gw;

        // ---- prologue: rows for sample s, label for sample s+nw ----
        int lbl0    = labels[s];           // wave-uniform -> s_load
        int lbl_nxt = labels[s + nw];
        const vfloat4* e0 = (const vfloat4*)(emb    + (size_t)s    * 512);
        const vfloat4* p0 = (const vfloat4*)(protos + (size_t)lbl0 * 512);
        vfloat4 ea = e0[lane], eb = e0[64 + lane];
        vfloat4 pa = p0[lane], pb = p0[64 + lane];

        // ---- steady state: issue next loads BEFORE reducing current ----
        for (int i = 0; i < iters - 2; ++i) {
            const int sn = s + nw;
            const int lbl_n2 = labels[s + 2 * nw];    // depth-2 label prefetch

            const vfloat4* e1 = (const vfloat4*)(emb    + (size_t)sn      * 512);
            const vfloat4* p1 = (const vfloat4*)(protos + (size_t)lbl_nxt * 512);
            vfloat4 ean = e1[lane], ebn = e1[64 + lane];
            vfloat4 pan = p1[lane], pbn = p1[64 + lane];

            float dot = dot4(ea, pa) + dot4(eb, pb);
            float esq = dot4(ea, ea) + dot4(eb, eb);
            float psq = dot4(pa, pa) + dot4(pb, pb);
            #pragma unroll
            for (int off = 32; off > 0; off >>= 1) {
                dot += __shfl_xor(dot, off, 64);
                esq += __shfl_xor(esq, off, 64);
                psq += __shfl_xor(psq, off, 64);
            }
            if (lane == 0) {
                float en = fmaxf(sqrtf(esq), COS_EPS);
                float pn = fmaxf(sqrtf(psq), COS_EPS);
                local += dot / (en * pn);
            }

            s = sn; lbl_nxt = lbl_n2;
            ea = ean; eb = ebn; pa = pan; pb = pbn;
        }

        // ---- epilogue iteration: load final rows, reduce current ----
        {
            const int sn = s + nw;
            const vfloat4* e1 = (const vfloat4*)(emb    + (size_t)sn      * 512);
            const vfloat4* p1 = (const vfloat4*)(protos + (size_t)lbl_nxt * 512);
            vfloat4 ean = e1[lane], ebn = e1[64 + lane];
            vfloat4 pan = p1[lane], pbn = p1[64 + lane];

            float dot = dot4(ea, pa) + dot4(eb, pb);
            float esq = dot4(ea, ea) + dot4(eb, eb);
            float psq = dot4(pa, pa) + dot4(pb, pb);
            #pragma unroll
            for (int off = 32; off > 0; off >>= 1) {
                dot += __shfl_xor(dot, off, 64);
                esq += __shfl_xor(esq, off, 64);
                psq += __shfl_xor(psq, off, 64);
            }
            if (lane == 0) {
                float en = fmaxf(sqrtf(esq), COS_EPS);
                float pn = fmaxf(sqrtf(psq), COS_EPS);
                local += dot / (en * pn);
            }
            ea = ean; eb = ebn; pa = pan; pb = pbn;
        }

        // ---- final sample ----
        {
            float dot = dot4(ea, pa) + dot4(eb, pb);
            float esq = dot4(ea, ea) + dot4(eb, eb);
            float psq = dot4(pa, pa) + dot4(pb, pb);
            #pragma unroll
            for (int off = 32; off > 0; off >>= 1) {
                dot += __shfl_xor(dot, off, 64);
                esq += __shfl_xor(esq, off, 64);
                psq += __shfl_xor(psq, off, 64);
            }
            if (lane == 0) {
                float en = fmaxf(sqrtf(esq), COS_EPS);
                float pn = fmaxf(sqrtf(psq), COS_EPS);
                local += dot / (en * pn);
            }
        }
    } else {
        // generic fallback (any D multiple of 256, any B)
        const int nchunks = D >> 8;
        for (int s = gw; s < B; s += nw) {
            const int lbl = labels[s];
            const vfloat4* e = (const vfloat4*)(emb    + (size_t)s   * (size_t)D);
            const vfloat4* p = (const vfloat4*)(protos + (size_t)lbl * (size_t)D);
            float dot = 0.f, esq = 0.f, psq = 0.f;
            for (int c = 0; c < nchunks; ++c) {
                vfloat4 ev = e[c * 64 + lane];
                vfloat4 pv = p[c * 64 + lane];
                dot += dot4(ev, pv);
                esq += dot4(ev, ev);
                psq += dot4(pv, pv);
            }
            #pragma unroll
            for (int off = 32; off > 0; off >>= 1) {
                dot += __shfl_xor(dot, off, 64);
                esq += __shfl_xor(esq, off, 64);
                psq += __shfl_xor(psq, off, 64);
            }
            if (lane == 0) {
                float en = fmaxf(sqrtf(esq), COS_EPS);
                float pn = fmaxf(sqrtf(psq), COS_EPS);
                local += dot / (en * pn);
            }
        }
    }

    // block reduction: one partial per wave -> LDS -> one atomic per block
    __shared__ float smem[8];
    if (lane == 0) smem[wib] = local;
    __syncthreads();
    if (threadIdx.x == 0) {
        float bs = 0.0f;
        for (int w = 0; w < wpb; ++w) bs += smem[w];
        atomicAdd(acc, bs);
    }
}

__global__ void assignment_loss_finalize(const float* __restrict__ acc,
                                         float* __restrict__ out,
                                         float invB)
{
    out[0] = 1.0f - acc[0] * invB;
}

extern "C" void kernel_launch(void* const* d_in, const int* in_sizes, int n_in,
                              void* d_out, int out_size, void* d_ws, size_t ws_size,
                              hipStream_t stream) {
    const float* emb    = (const float*)d_in[0];   // [B, D] float32
    const int*   labels = (const int*)  d_in[1];   // [B]
    const float* protos = (const float*)d_in[2];   // [C, D] float32
    float*       out    = (float*)d_out;           // scalar float32
    float*       acc    = (float*)d_ws;

    const int B = in_sizes[1];
    const int D = in_sizes[0] / B;                 // 512

    hipMemsetAsync(acc, 0, sizeof(float), stream); // d_ws poisoned 0xAA each call

    const int block = 256;                         // 4 waves/block
    const int grid  = 1024;                        // R1's proven config: 4096 waves
    assignment_loss_kernel<<<grid, block, 0, stream>>>(emb, labels, protos, acc, B, D);
    assignment_loss_finalize<<<1, 1, 0, stream>>>(acc, out, 1.0f / (float)B);
}